// Round 14
// baseline (77.219 us; speedup 1.0000x reference)
//
#include <hip/hip_runtime.h>

#define DIM 128
#define NBC 128        // edge chunks
#define SP 6252        // padded u32 words per (class,half,chunk) slice (>= nhalf/4, mult of 4)

typedef __attribute__((ext_vector_type(8))) short bf16x8;
typedef __attribute__((ext_vector_type(4))) float f32x4;

static __device__ inline short f2bf(float f) {
    union { float f; unsigned u; } x;
    x.f = f;
    unsigned r = (x.u + 0x7FFF + ((x.u >> 16) & 1)) >> 16;  // RNE
    return (short)r;
}
static __device__ inline float bflo(unsigned u) {
    union { unsigned u; float f; } x; x.u = u << 16; return x.f;
}
static __device__ inline float bfhi(unsigned u) {
    union { unsigned u; float f; } x; x.u = u & 0xFFFF0000u; return x.f;
}

// ---------------- half-range u8 histogram ----------------
__global__ __launch_bounds__(512) void k_hist(
    const int* __restrict__ src, const int* __restrict__ dst,
    unsigned* __restrict__ partial, int n_edges, int nhalf, int chunk) {
    __shared__ unsigned hist[SP];
    int b = blockIdx.x & (NBC - 1);
    int h = (blockIdx.x >> 7) & 1;
    int cls = blockIdx.x >> 8;
    const int* __restrict__ idx = cls ? dst : src;
    int lo = h * nhalf;

    for (int i = threadIdx.x * 4; i < SP; i += 512 * 4)
        *(uint4*)&hist[i] = make_uint4(0, 0, 0, 0);
    __syncthreads();

    int e0 = b * chunk;
    int e1 = min(e0 + chunk, n_edges);
    int qs = e0 >> 2, qe = e1 >> 2;
#define CNT(x)                                                                     \
    {                                                                              \
        unsigned t = (unsigned)((x) - lo);                                         \
        if (t < (unsigned)nhalf) atomicAdd(&hist[t >> 2], 1u << ((t & 3) * 8));    \
    }
    for (int q = qs + threadIdx.x; q < qe; q += 512) {
        int4 v = ((const int4*)idx)[q];
        CNT(v.x); CNT(v.y); CNT(v.z); CNT(v.w);
    }
    for (int e = (qe << 2) + threadIdx.x; e < e1; e += 512) CNT(idx[e]);
#undef CNT
    __syncthreads();

    unsigned* dp = partial + (size_t)((cls * 2 + h) * NBC + b) * SP;
    for (int i = threadIdx.x * 4; i < SP; i += 512 * 4)
        *(uint4*)&dp[i] = *(const uint4*)&hist[i];
}

// ---------------- reduce (byte-parallel) + fused local scan ----------------
__global__ __launch_bounds__(256) void k_hreduce(
    unsigned* __restrict__ partial, float* __restrict__ rso,
    int* __restrict__ deg, float* __restrict__ ri, int* __restrict__ map,
    int* __restrict__ off0, int* __restrict__ blksum,
    int nhalf, int nbh, int n_fine, int n_coarse) {
    int g = blockIdx.x;
    int cls = g / (2 * nbh);
    int rem = g - cls * (2 * nbh);
    int h = rem / nbh;
    int blk = rem - h * nbh;
    int hw = nhalf / 4;
    int w = blk * 256 + threadIdx.x;
    bool valid = (w < hw);

    if (cls == 0) {  // src class -> rso
        if (!valid) return;
        unsigned s = 0;
        const unsigned* p = partial + (size_t)(h * NBC) * SP + w;
#pragma unroll 8
        for (int b = 0; b < NBC; ++b) s += p[(size_t)b * SP];
        int i0 = h * nhalf + 4 * w;
        int dd[4] = {(int)(s & 255), (int)((s >> 8) & 255), (int)((s >> 16) & 255), (int)(s >> 24)};
        for (int k = 0; k < 4 && i0 + k < n_fine; ++k)
            rso[i0 + k] = rsqrtf((float)max(dd[k], 1));
        return;
    }

    __shared__ int sL[256];
    unsigned run = 0;
    if (valid) {
        unsigned* p = partial + (size_t)((2 + h) * NBC) * SP + w;
#pragma unroll 8
        for (int b = 0; b < NBC; ++b) {
            unsigned* q = p + (size_t)b * SP;
            unsigned t = *q;
            *q = run;  // exclusive per-chunk prefix, byte-parallel (totals < 256)
            run += t;
        }
    }
    int d0 = run & 255, d1 = (run >> 8) & 255, d2 = (run >> 16) & 255, d3 = run >> 24;
    int mysum = valid ? (d0 + d1 + d2 + d3) : 0;
    int t = threadIdx.x;
    sL[t] = mysum;
    __syncthreads();
    for (int dd = 1; dd < 256; dd <<= 1) {
        int x = (t >= dd) ? sL[t - dd] : 0;
        __syncthreads();
        if (t >= dd) sL[t] += x;
        __syncthreads();
    }
    int excl = sL[t] - mysum;
    if (t == 255) blksum[h * nbh + blk] = sL[255];
    if (valid) {
        int i0 = h * nhalf + 4 * w;
        int dd[4] = {d0, d1, d2, d3};
        int pf[4] = {excl, excl + d0, excl + d0 + d1, excl + d0 + d1 + d2};
        for (int k = 0; k < 4 && i0 + k < n_fine; ++k) {
            deg[i0 + k] = dd[k];
            ri[i0 + k] = rsqrtf((float)max(dd[k], 1));
            map[i0 + k] = n_coarse;
            off0[i0 + k] = pf[k];
        }
    }
}

// ---------------- scanadd: off0 -> GLOBAL CSR offsets (fold window scan in) ----------------
__global__ __launch_bounds__(256) void k_scanadd(
    int* __restrict__ off0, const int* __restrict__ blksum,
    int n_fine, int nhalf, int nbh, int nbw) {
    __shared__ int bscan[64];
    int t = threadIdx.x;
    if (t < 64) {  // redundant per-block exclusive wave-scan of blksum (nbw <= 64)
        int orig = (t < nbw) ? blksum[t] : 0;
        int v = orig;
#pragma unroll
        for (int dd = 1; dd < 64; dd <<= 1) {
            int x = __shfl_up(v, dd, 64);
            if (t >= dd) v += x;
        }
        bscan[t] = v - orig;
    }
    __syncthreads();
    int v = blockIdx.x * 256 + t;
    if (v < n_fine) {
        int hh = (v >= nhalf) ? 1 : 0;
        int widx = hh * nbh + ((v - hh * nhalf) >> 10);
        off0[v] += bscan[widx];
    }
}

// ---------------- MFMA GEMM -> bf16 hw; 2 tiles/iteration; fused map scatter, zero row ----------------
__global__ __launch_bounds__(256) void k_gemm(
    const float* __restrict__ feat, const int* __restrict__ sel,
    const float* __restrict__ rso, const float* __restrict__ W,
    unsigned short* __restrict__ hwb, int* __restrict__ map, int n_coarse) {
    __shared__ short Wl[16384];  // 32 KiB, B-fragment order
    int t = threadIdx.x;

    if (blockIdx.x == 0 && t < DIM) hwb[(size_t)n_coarse * DIM + t] = 0;  // zero row
    for (int gi = blockIdx.x * 256 + t; gi < n_coarse; gi += gridDim.x * 256)
        map[sel[gi]] = gi;  // map scatter

    for (int g = t; g < 2048; g += 256) {
        int n = g & 127;
        int kk = g >> 7;
        int kbase = ((kk >> 2) * 32) + ((kk & 3) * 8);
        bf16x8 v;
#pragma unroll
        for (int j = 0; j < 8; ++j) v[j] = f2bf(W[(size_t)(kbase + j) * DIM + n]);
        *(bf16x8*)&Wl[g * 8] = v;
    }
    __syncthreads();

    int wv = t >> 6, lane = t & 63;
    int lg = lane >> 4;
    int lm = lane & 15;
    int ntiles = (n_coarse + 15) / 16;
    int ntp = (ntiles + 1) >> 1;  // tile pairs
    for (int tp = blockIdx.x * 4 + wv; tp < ntp; tp += gridDim.x * 4) {
        int t0 = tp * 2, t1 = tp * 2 + 1;
        int r0 = t0 * 16, r1 = t1 * 16;
        int ra0 = min(r0 + lm, n_coarse - 1);
        int ra1 = min(r1 + lm, n_coarse - 1);
        const float* fr0 = feat + (size_t)ra0 * DIM;
        const float* fr1 = feat + (size_t)ra1 * DIM;
        bf16x8 a0[4], a1[4];
        // Both tiles' A-loads issued up front: tile1 loads overlap tile0 MFMAs.
#pragma unroll
        for (int kc = 0; kc < 4; ++kc) {
            float4 x0 = *(const float4*)(fr0 + kc * 32 + lg * 8);
            float4 x1 = *(const float4*)(fr0 + kc * 32 + lg * 8 + 4);
            bf16x8 av;
            av[0] = f2bf(x0.x); av[1] = f2bf(x0.y); av[2] = f2bf(x0.z); av[3] = f2bf(x0.w);
            av[4] = f2bf(x1.x); av[5] = f2bf(x1.y); av[6] = f2bf(x1.z); av[7] = f2bf(x1.w);
            a0[kc] = av;
        }
#pragma unroll
        for (int kc = 0; kc < 4; ++kc) {
            float4 x0 = *(const float4*)(fr1 + kc * 32 + lg * 8);
            float4 x1 = *(const float4*)(fr1 + kc * 32 + lg * 8 + 4);
            bf16x8 av;
            av[0] = f2bf(x0.x); av[1] = f2bf(x0.y); av[2] = f2bf(x0.z); av[3] = f2bf(x0.w);
            av[4] = f2bf(x1.x); av[5] = f2bf(x1.y); av[6] = f2bf(x1.z); av[7] = f2bf(x1.w);
            a1[kc] = av;
        }
        f32x4 acc[8];
#pragma unroll
        for (int cb = 0; cb < 8; ++cb) acc[cb] = (f32x4){0.f, 0.f, 0.f, 0.f};
#pragma unroll
        for (int kc = 0; kc < 4; ++kc) {
#pragma unroll
            for (int cb = 0; cb < 8; ++cb) {
                bf16x8 b = *(const bf16x8*)&Wl[(((kc * 4 + lg) * 128) + cb * 16 + lm) * 8];
                acc[cb] = __builtin_amdgcn_mfma_f32_16x16x32_bf16(a0[kc], b, acc[cb], 0, 0, 0);
            }
        }
#pragma unroll
        for (int j = 0; j < 4; ++j) {
            int r = r0 + lg * 4 + j;
            if (r < n_coarse) {
                float sc = rso[sel[r]];
                unsigned short* hr = hwb + (size_t)r * DIM + lm;
#pragma unroll
                for (int cb = 0; cb < 8; ++cb)
                    hr[cb * 16] = (unsigned short)f2bf(acc[cb][j] * sc);
            }
        }
        if (t1 < ntiles) {
#pragma unroll
            for (int cb = 0; cb < 8; ++cb) acc[cb] = (f32x4){0.f, 0.f, 0.f, 0.f};
#pragma unroll
            for (int kc = 0; kc < 4; ++kc) {
#pragma unroll
                for (int cb = 0; cb < 8; ++cb) {
                    bf16x8 b = *(const bf16x8*)&Wl[(((kc * 4 + lg) * 128) + cb * 16 + lm) * 8];
                    acc[cb] = __builtin_amdgcn_mfma_f32_16x16x32_bf16(a1[kc], b, acc[cb], 0, 0, 0);
                }
            }
#pragma unroll
            for (int j = 0; j < 4; ++j) {
                int r = r1 + lg * 4 + j;
                if (r < n_coarse) {
                    float sc = rso[sel[r]];
                    unsigned short* hr = hwb + (size_t)r * DIM + lm;
#pragma unroll
                    for (int cb = 0; cb < 8; ++cb)
                        hr[cb * 16] = (unsigned short)f2bf(acc[cb][j] * sc);
                }
            }
        }
    }
}

// ---------------- bucket: quarter-range u8 LDS counting sort (global off0) ----------------
__global__ __launch_bounds__(512) void k_bucket(
    const int* __restrict__ src, const int* __restrict__ dst, const int* __restrict__ map,
    const int* __restrict__ off0, const unsigned* __restrict__ partial,
    int* __restrict__ bucket, int n_edges, int nhalf, int chunk) {
    __shared__ unsigned cur[3125];
    int b = blockIdx.x & (NBC - 1);
    int q = blockIdx.x >> 7;      // 0..3
    int h = q >> 1;
    int qw = nhalf / 8;           // 3125 words per quarter
    int qrange = nhalf / 2;       // nodes per quarter
    const unsigned* pfx = partial + (size_t)((2 + h) * NBC + b) * SP + (q & 1) * qw;
    for (int i = threadIdx.x; i < qw; i += 512) cur[i] = pfx[i];
    __syncthreads();

    int lo = q * qrange;
    int e0 = b * chunk;
    int e1 = min(e0 + chunk, n_edges);
    int qs = e0 >> 2, qe = e1 >> 2;
#define PROC(d, s)                                                                 \
    {                                                                              \
        unsigned t = (unsigned)((d) - lo);                                         \
        if (t < (unsigned)qrange) {                                                \
            int sh = (t & 3) * 8;                                                  \
            unsigned old = atomicAdd(&cur[t >> 2], 1u << sh);                      \
            bucket[off0[d] + (int)((old >> sh) & 255)] = map[s];                   \
        }                                                                          \
    }
    for (int qq = qs + threadIdx.x; qq < qe; qq += 512) {
        int4 d4 = ((const int4*)dst)[qq];
        int4 s4 = ((const int4*)src)[qq];
        PROC(d4.x, s4.x); PROC(d4.y, s4.y); PROC(d4.z, s4.z); PROC(d4.w, s4.w);
    }
    for (int e = (qe << 2) + threadIdx.x; e < e1; e += 512) PROC(dst[e], src[e]);
#undef PROC
}

// ---------------- gather: 16 lanes per node; batched index loads + shfl distribute ----------------
__global__ __launch_bounds__(256) void k_gather(
    const int* __restrict__ off0, const int* __restrict__ deg,
    const float* __restrict__ ri, const int* __restrict__ bucket,
    const uint4* __restrict__ hwb4, const float* __restrict__ bias,
    float* __restrict__ out, int n_fine) {
    int gid = blockIdx.x * 256 + threadIdx.x;
    int lane = threadIdx.x & 63;
    int l = gid & 15;            // column group: cols l*8 .. l*8+7 (== index slot in batch)
    int grp = gid >> 4;
    int ngrp = (gridDim.x * 256) >> 4;
    int gbase = lane & 48;       // group base lane within wave (0,16,32,48)
    float4 b0 = ((const float4*)bias)[l * 2];
    float4 b1 = ((const float4*)bias)[l * 2 + 1];
    for (int v = grp; v < n_fine; v += ngrp) {
        int o = off0[v];
        int n = deg[v];
        float a0 = 0, a1 = 0, a2 = 0, a3 = 0, a4 = 0, a5 = 0, a6 = 0, a7 = 0;
        float c0 = 0, c1 = 0, c2 = 0, c3 = 0, c4 = 0, c5 = 0, c6 = 0, c7 = 0;
        for (int jb = 0; jb < n; jb += 16) {
            int ent = __builtin_nontemporal_load(bucket + o + jb + l);
            int m = min(n - jb, 16);
            int j = 0;
            for (; j + 2 <= m; j += 2) {
                int i0 = __shfl(ent, gbase + j, 64);
                int i1 = __shfl(ent, gbase + j + 1, 64);
                uint4 u0 = hwb4[(size_t)i0 * 16 + l];
                uint4 u1 = hwb4[(size_t)i1 * 16 + l];
                a0 += bflo(u0.x); a1 += bfhi(u0.x); a2 += bflo(u0.y); a3 += bfhi(u0.y);
                a4 += bflo(u0.z); a5 += bfhi(u0.z); a6 += bflo(u0.w); a7 += bfhi(u0.w);
                c0 += bflo(u1.x); c1 += bfhi(u1.x); c2 += bflo(u1.y); c3 += bfhi(u1.y);
                c4 += bflo(u1.z); c5 += bfhi(u1.z); c6 += bflo(u1.w); c7 += bfhi(u1.w);
            }
            if (j < m) {
                int i0 = __shfl(ent, gbase + j, 64);
                uint4 u0 = hwb4[(size_t)i0 * 16 + l];
                a0 += bflo(u0.x); a1 += bfhi(u0.x); a2 += bflo(u0.y); a3 += bfhi(u0.y);
                a4 += bflo(u0.z); a5 += bfhi(u0.z); a6 += bflo(u0.w); a7 += bfhi(u0.w);
            }
        }
        float s = ri[v];
        f32x4 r0, r1;
        r0.x = (a0 + c0) * s + b0.x; r0.y = (a1 + c1) * s + b0.y;
        r0.z = (a2 + c2) * s + b0.z; r0.w = (a3 + c3) * s + b0.w;
        r1.x = (a4 + c4) * s + b1.x; r1.y = (a5 + c5) * s + b1.y;
        r1.z = (a6 + c6) * s + b1.z; r1.w = (a7 + c7) * s + b1.w;
        __builtin_nontemporal_store(r0, (f32x4*)(out + (size_t)v * DIM + l * 8));
        __builtin_nontemporal_store(r1, (f32x4*)(out + (size_t)v * DIM + l * 8 + 4));
    }
}

extern "C" void kernel_launch(void* const* d_in, const int* in_sizes, int n_in,
                              void* d_out, int out_size, void* d_ws, size_t ws_size,
                              hipStream_t stream) {
    const float* feat = (const float*)d_in[0];
    const int* src = (const int*)d_in[1];
    const int* dst = (const int*)d_in[2];
    const int* sel = (const int*)d_in[3];
    const float* W = (const float*)d_in[4];
    const float* bias = (const float*)d_in[5];
    float* out = (float*)d_out;

    int n_fine = out_size / DIM;       // 50000
    int n_coarse = in_sizes[0] / DIM;  // 25000
    int n_edges = in_sizes[1];         // 800000

    int nhalf = ((n_fine / 2) + 3) & ~3;              // 25000 (mult of 4)
    int nbh = (nhalf / 4 + 255) / 256;                // 25 windows per half
    int nbw = 2 * nbh;                                // 50 total windows
    int chunk = ((n_edges + NBC - 1) / NBC + 3) & ~3; // 6252, int4-aligned

    // Workspace
    int* map = (int*)d_ws;                      // [n_fine]
    int* off0 = map + n_fine;                   // [n_fine]
    int* deg = off0 + n_fine;                   // [n_fine]
    float* ri = (float*)(deg + n_fine);         // [n_fine]
    float* rso = ri + n_fine;                   // [n_fine]
    int* blksum = (int*)(rso + n_fine);         // [64]
    unsigned short* hwb = (unsigned short*)(blksum + 64);     // [(n_coarse+1)*DIM] bf16
    int* bucket = (int*)(hwb + (size_t)(n_coarse + 1) * DIM); // [n_edges]
    unsigned* partial = (unsigned*)(bucket + n_edges);        // [2*2*NBC*SP] u32

    int ntiles = (n_coarse + 15) / 16;
    int ntp = (ntiles + 1) / 2;

    hipLaunchKernelGGL(k_hist, dim3(4 * NBC), dim3(512), 0, stream,
                       src, dst, partial, n_edges, nhalf, chunk);
    hipLaunchKernelGGL(k_hreduce, dim3(4 * nbh), dim3(256), 0, stream,
                       partial, rso, deg, ri, map, off0, blksum, nhalf, nbh, n_fine, n_coarse);
    hipLaunchKernelGGL(k_scanadd, dim3((n_fine + 255) / 256), dim3(256), 0, stream,
                       off0, blksum, n_fine, nhalf, nbh, nbw);
    hipLaunchKernelGGL(k_gemm, dim3((ntp + 3) / 4), dim3(256), 0, stream,
                       feat, sel, rso, W, hwb, map, n_coarse);
    hipLaunchKernelGGL(k_bucket, dim3(4 * NBC), dim3(512), 0, stream,
                       src, dst, map, off0, partial, bucket, n_edges, nhalf, chunk);
    hipLaunchKernelGGL(k_gather, dim3((n_fine * 16 + 255) / 256), dim3(256), 0, stream,
                       off0, deg, ri, bucket, (const uint4*)hwb, bias, out, n_fine);
}

// Round 15
// 72.699 us; speedup vs baseline: 1.0622x; 1.0622x over previous
//
#include <hip/hip_runtime.h>

#define DIM 128
#define NBC 128        // edge chunks
#define SP 6252        // padded u32 words per (class,half,chunk) slice (>= nhalf/4, mult of 4)

typedef __attribute__((ext_vector_type(8))) short bf16x8;
typedef __attribute__((ext_vector_type(4))) float f32x4;

static __device__ inline short f2bf(float f) {
    union { float f; unsigned u; } x;
    x.f = f;
    unsigned r = (x.u + 0x7FFF + ((x.u >> 16) & 1)) >> 16;  // RNE
    return (short)r;
}
static __device__ inline float bflo(unsigned u) {
    union { unsigned u; float f; } x; x.u = u << 16; return x.f;
}
static __device__ inline float bfhi(unsigned u) {
    union { unsigned u; float f; } x; x.u = u & 0xFFFF0000u; return x.f;
}

// ---------------- half-range u8 histogram ----------------
__global__ __launch_bounds__(512) void k_hist(
    const int* __restrict__ src, const int* __restrict__ dst,
    unsigned* __restrict__ partial, int n_edges, int nhalf, int chunk) {
    __shared__ unsigned hist[SP];
    int b = blockIdx.x & (NBC - 1);
    int h = (blockIdx.x >> 7) & 1;
    int cls = blockIdx.x >> 8;
    const int* __restrict__ idx = cls ? dst : src;
    int lo = h * nhalf;

    for (int i = threadIdx.x * 4; i < SP; i += 512 * 4)
        *(uint4*)&hist[i] = make_uint4(0, 0, 0, 0);
    __syncthreads();

    int e0 = b * chunk;
    int e1 = min(e0 + chunk, n_edges);
    int qs = e0 >> 2, qe = e1 >> 2;
#define CNT(x)                                                                     \
    {                                                                              \
        unsigned t = (unsigned)((x) - lo);                                         \
        if (t < (unsigned)nhalf) atomicAdd(&hist[t >> 2], 1u << ((t & 3) * 8));    \
    }
    for (int q = qs + threadIdx.x; q < qe; q += 512) {
        int4 v = ((const int4*)idx)[q];
        CNT(v.x); CNT(v.y); CNT(v.z); CNT(v.w);
    }
    for (int e = (qe << 2) + threadIdx.x; e < e1; e += 512) CNT(idx[e]);
#undef CNT
    __syncthreads();

    unsigned* dp = partial + (size_t)((cls * 2 + h) * NBC + b) * SP;
    for (int i = threadIdx.x * 4; i < SP; i += 512 * 4)
        *(uint4*)&dp[i] = *(const uint4*)&hist[i];
}

// ---------------- reduce (byte-parallel) + fused local scan ----------------
__global__ __launch_bounds__(256) void k_hreduce(
    unsigned* __restrict__ partial, float* __restrict__ rso,
    int* __restrict__ deg, float* __restrict__ ri, int* __restrict__ map,
    int* __restrict__ off0, int* __restrict__ blksum,
    int nhalf, int nbh, int n_fine, int n_coarse) {
    int g = blockIdx.x;
    int cls = g / (2 * nbh);
    int rem = g - cls * (2 * nbh);
    int h = rem / nbh;
    int blk = rem - h * nbh;
    int hw = nhalf / 4;
    int w = blk * 256 + threadIdx.x;
    bool valid = (w < hw);

    if (cls == 0) {  // src class -> rso
        if (!valid) return;
        unsigned s = 0;
        const unsigned* p = partial + (size_t)(h * NBC) * SP + w;
#pragma unroll 8
        for (int b = 0; b < NBC; ++b) s += p[(size_t)b * SP];
        int i0 = h * nhalf + 4 * w;
        int dd[4] = {(int)(s & 255), (int)((s >> 8) & 255), (int)((s >> 16) & 255), (int)(s >> 24)};
        for (int k = 0; k < 4 && i0 + k < n_fine; ++k)
            rso[i0 + k] = rsqrtf((float)max(dd[k], 1));
        return;
    }

    __shared__ int sL[256];
    unsigned run = 0;
    if (valid) {
        unsigned* p = partial + (size_t)((2 + h) * NBC) * SP + w;
#pragma unroll 8
        for (int b = 0; b < NBC; ++b) {
            unsigned* q = p + (size_t)b * SP;
            unsigned t = *q;
            *q = run;  // exclusive per-chunk prefix, byte-parallel (totals < 256)
            run += t;
        }
    }
    int d0 = run & 255, d1 = (run >> 8) & 255, d2 = (run >> 16) & 255, d3 = run >> 24;
    int mysum = valid ? (d0 + d1 + d2 + d3) : 0;
    int t = threadIdx.x;
    sL[t] = mysum;
    __syncthreads();
    for (int dd = 1; dd < 256; dd <<= 1) {
        int x = (t >= dd) ? sL[t - dd] : 0;
        __syncthreads();
        if (t >= dd) sL[t] += x;
        __syncthreads();
    }
    int excl = sL[t] - mysum;
    if (t == 255) blksum[h * nbh + blk] = sL[255];
    if (valid) {
        int i0 = h * nhalf + 4 * w;
        int dd[4] = {d0, d1, d2, d3};
        int pf[4] = {excl, excl + d0, excl + d0 + d1, excl + d0 + d1 + d2};
        for (int k = 0; k < 4 && i0 + k < n_fine; ++k) {
            deg[i0 + k] = dd[k];
            ri[i0 + k] = rsqrtf((float)max(dd[k], 1));
            map[i0 + k] = n_coarse;
            off0[i0 + k] = pf[k];
        }
    }
}

// ---------------- MFMA GEMM -> bf16 hw; fused: map scatter, blksum scan, zero row ----------------
__global__ __launch_bounds__(256) void k_gemm(
    const float* __restrict__ feat, const int* __restrict__ sel,
    const float* __restrict__ rso, const float* __restrict__ W,
    unsigned short* __restrict__ hwb, int* __restrict__ map,
    int* __restrict__ blksum, int n_coarse, int nbw) {
    __shared__ short Wl[16384];  // 32 KiB, B-fragment order
    int t = threadIdx.x;

    if (blockIdx.x == 0) {
        if (t < 64) {  // wave-scan of blksum -> exclusive
            int orig = (t < nbw) ? blksum[t] : 0;
            int v = orig;
#pragma unroll
            for (int dd = 1; dd < 64; dd <<= 1) {
                int x = __shfl_up(v, dd, 64);
                if (t >= dd) v += x;
            }
            if (t < nbw) blksum[t] = v - orig;
        }
        if (t < DIM) hwb[(size_t)n_coarse * DIM + t] = 0;  // zero row
    }
    for (int gi = blockIdx.x * 256 + t; gi < n_coarse; gi += gridDim.x * 256)
        map[sel[gi]] = gi;  // map scatter

    for (int g = t; g < 2048; g += 256) {
        int n = g & 127;
        int kk = g >> 7;
        int kbase = ((kk >> 2) * 32) + ((kk & 3) * 8);
        bf16x8 v;
#pragma unroll
        for (int j = 0; j < 8; ++j) v[j] = f2bf(W[(size_t)(kbase + j) * DIM + n]);
        *(bf16x8*)&Wl[g * 8] = v;
    }
    __syncthreads();

    int wv = t >> 6, lane = t & 63;
    int lg = lane >> 4;
    int lm = lane & 15;
    int ntiles = (n_coarse + 15) / 16;
    for (int tile = blockIdx.x * 4 + wv; tile < ntiles; tile += gridDim.x * 4) {
        int r0 = tile * 16;
        int ra = min(r0 + lm, n_coarse - 1);
        const float* fr = feat + (size_t)ra * DIM;
        bf16x8 a[4];
#pragma unroll
        for (int kc = 0; kc < 4; ++kc) {
            float4 x0 = *(const float4*)(fr + kc * 32 + lg * 8);
            float4 x1 = *(const float4*)(fr + kc * 32 + lg * 8 + 4);
            bf16x8 av;
            av[0] = f2bf(x0.x); av[1] = f2bf(x0.y); av[2] = f2bf(x0.z); av[3] = f2bf(x0.w);
            av[4] = f2bf(x1.x); av[5] = f2bf(x1.y); av[6] = f2bf(x1.z); av[7] = f2bf(x1.w);
            a[kc] = av;
        }
        f32x4 acc[8];
#pragma unroll
        for (int cb = 0; cb < 8; ++cb) acc[cb] = (f32x4){0.f, 0.f, 0.f, 0.f};
#pragma unroll
        for (int kc = 0; kc < 4; ++kc) {
#pragma unroll
            for (int cb = 0; cb < 8; ++cb) {
                bf16x8 b = *(const bf16x8*)&Wl[(((kc * 4 + lg) * 128) + cb * 16 + lm) * 8];
                acc[cb] = __builtin_amdgcn_mfma_f32_16x16x32_bf16(a[kc], b, acc[cb], 0, 0, 0);
            }
        }
#pragma unroll
        for (int j = 0; j < 4; ++j) {
            int r = r0 + lg * 4 + j;
            if (r < n_coarse) {
                float sc = rso[sel[r]];
                unsigned short* hr = hwb + (size_t)r * DIM + lm;
#pragma unroll
                for (int cb = 0; cb < 8; ++cb)
                    hr[cb * 16] = (unsigned short)f2bf(acc[cb][j] * sc);
            }
        }
    }
}

// ---------------- bucket: quarter-range u8 LDS counting sort ----------------
__global__ __launch_bounds__(512) void k_bucket(
    const int* __restrict__ src, const int* __restrict__ dst, const int* __restrict__ map,
    const int* __restrict__ off0, const int* __restrict__ blksum,
    const unsigned* __restrict__ partial,
    int* __restrict__ bucket, int n_edges, int nhalf, int nbh, int chunk) {
    __shared__ unsigned cur[3125];
    int b = blockIdx.x & (NBC - 1);
    int q = blockIdx.x >> 7;      // 0..3
    int h = q >> 1;
    int qw = nhalf / 8;           // 3125 words per quarter
    int qrange = nhalf / 2;       // nodes per quarter
    const unsigned* pfx = partial + (size_t)((2 + h) * NBC + b) * SP + (q & 1) * qw;
    for (int i = threadIdx.x; i < qw; i += 512) cur[i] = pfx[i];
    __syncthreads();

    int lo = q * qrange;
    int e0 = b * chunk;
    int e1 = min(e0 + chunk, n_edges);
    int qs = e0 >> 2, qe = e1 >> 2;
#define PROC(d, s)                                                                 \
    {                                                                              \
        unsigned t = (unsigned)((d) - lo);                                         \
        if (t < (unsigned)qrange) {                                                \
            int sh = (t & 3) * 8;                                                  \
            unsigned old = atomicAdd(&cur[t >> 2], 1u << sh);                      \
            int widx = h * nbh + (((d) - h * nhalf) >> 10);                        \
            bucket[off0[d] + blksum[widx] + (int)((old >> sh) & 255)] = map[s];    \
        }                                                                          \
    }
    for (int qq = qs + threadIdx.x; qq < qe; qq += 512) {
        int4 d4 = ((const int4*)dst)[qq];
        int4 s4 = ((const int4*)src)[qq];
        PROC(d4.x, s4.x); PROC(d4.y, s4.y); PROC(d4.z, s4.z); PROC(d4.w, s4.w);
    }
    for (int e = (qe << 2) + threadIdx.x; e < e1; e += 512) PROC(dst[e], src[e]);
#undef PROC
}

// ---------------- gather: 16 lanes per node; batched index loads + shfl distribute ----------------
// Per 16-edge batch: ONE coalesced index load (lane l -> bucket[o+jb+l]), then row
// indices distributed via __shfl (VALU). Row gathers within a batch are independent
// -> they pipeline instead of serializing on L2 round-trips.
__global__ __launch_bounds__(256) void k_gather(
    const int* __restrict__ off0, const int* __restrict__ blksum,
    const int* __restrict__ deg, const float* __restrict__ ri,
    const int* __restrict__ bucket, const uint4* __restrict__ hwb4,
    const float* __restrict__ bias, float* __restrict__ out,
    int n_fine, int nhalf, int nbh) {
    int gid = blockIdx.x * 256 + threadIdx.x;
    int lane = threadIdx.x & 63;
    int l = gid & 15;            // column group: cols l*8 .. l*8+7 (== index slot in batch)
    int grp = gid >> 4;
    int ngrp = (gridDim.x * 256) >> 4;
    int gbase = lane & 48;       // group base lane within wave (0,16,32,48)
    float4 b0 = ((const float4*)bias)[l * 2];
    float4 b1 = ((const float4*)bias)[l * 2 + 1];
    for (int v = grp; v < n_fine; v += ngrp) {
        int hh = (v >= nhalf) ? 1 : 0;
        int widx = hh * nbh + ((v - hh * nhalf) >> 10);
        int o = off0[v] + blksum[widx];
        int n = deg[v];
        float a0 = 0, a1 = 0, a2 = 0, a3 = 0, a4 = 0, a5 = 0, a6 = 0, a7 = 0;
        float c0 = 0, c1 = 0, c2 = 0, c3 = 0, c4 = 0, c5 = 0, c6 = 0, c7 = 0;
        for (int jb = 0; jb < n; jb += 16) {
            // one coalesced load fetches 16 indices for this node (lane l -> entry jb+l).
            // May read up to 14 ints past this node's range (into next node's entries /
            // past the last node into the adjacent ws buffer) - masked by m below.
            int ent = __builtin_nontemporal_load(bucket + o + jb + l);
            int m = min(n - jb, 16);
            int j = 0;
            for (; j + 2 <= m; j += 2) {
                int i0 = __shfl(ent, gbase + j, 64);
                int i1 = __shfl(ent, gbase + j + 1, 64);
                uint4 u0 = hwb4[(size_t)i0 * 16 + l];
                uint4 u1 = hwb4[(size_t)i1 * 16 + l];
                a0 += bflo(u0.x); a1 += bfhi(u0.x); a2 += bflo(u0.y); a3 += bfhi(u0.y);
                a4 += bflo(u0.z); a5 += bfhi(u0.z); a6 += bflo(u0.w); a7 += bfhi(u0.w);
                c0 += bflo(u1.x); c1 += bfhi(u1.x); c2 += bflo(u1.y); c3 += bfhi(u1.y);
                c4 += bflo(u1.z); c5 += bfhi(u1.z); c6 += bflo(u1.w); c7 += bfhi(u1.w);
            }
            if (j < m) {
                int i0 = __shfl(ent, gbase + j, 64);
                uint4 u0 = hwb4[(size_t)i0 * 16 + l];
                a0 += bflo(u0.x); a1 += bfhi(u0.x); a2 += bflo(u0.y); a3 += bfhi(u0.y);
                a4 += bflo(u0.z); a5 += bfhi(u0.z); a6 += bflo(u0.w); a7 += bfhi(u0.w);
            }
        }
        float s = ri[v];
        f32x4 r0, r1;
        r0.x = (a0 + c0) * s + b0.x; r0.y = (a1 + c1) * s + b0.y;
        r0.z = (a2 + c2) * s + b0.z; r0.w = (a3 + c3) * s + b0.w;
        r1.x = (a4 + c4) * s + b1.x; r1.y = (a5 + c5) * s + b1.y;
        r1.z = (a6 + c6) * s + b1.z; r1.w = (a7 + c7) * s + b1.w;
        __builtin_nontemporal_store(r0, (f32x4*)(out + (size_t)v * DIM + l * 8));
        __builtin_nontemporal_store(r1, (f32x4*)(out + (size_t)v * DIM + l * 8 + 4));
    }
}

extern "C" void kernel_launch(void* const* d_in, const int* in_sizes, int n_in,
                              void* d_out, int out_size, void* d_ws, size_t ws_size,
                              hipStream_t stream) {
    const float* feat = (const float*)d_in[0];
    const int* src = (const int*)d_in[1];
    const int* dst = (const int*)d_in[2];
    const int* sel = (const int*)d_in[3];
    const float* W = (const float*)d_in[4];
    const float* bias = (const float*)d_in[5];
    float* out = (float*)d_out;

    int n_fine = out_size / DIM;       // 50000
    int n_coarse = in_sizes[0] / DIM;  // 25000
    int n_edges = in_sizes[1];         // 800000

    int nhalf = ((n_fine / 2) + 3) & ~3;              // 25000 (mult of 4)
    int nbh = (nhalf / 4 + 255) / 256;                // 25 windows per half
    int nbw = 2 * nbh;                                // 50 total windows
    int chunk = ((n_edges + NBC - 1) / NBC + 3) & ~3; // 6252, int4-aligned

    // Workspace
    int* map = (int*)d_ws;                      // [n_fine]
    int* off0 = map + n_fine;                   // [n_fine]
    int* deg = off0 + n_fine;                   // [n_fine]
    float* ri = (float*)(deg + n_fine);         // [n_fine]
    float* rso = ri + n_fine;                   // [n_fine]
    int* blksum = (int*)(rso + n_fine);         // [64]
    unsigned short* hwb = (unsigned short*)(blksum + 64);     // [(n_coarse+1)*DIM] bf16
    int* bucket = (int*)(hwb + (size_t)(n_coarse + 1) * DIM); // [n_edges]
    unsigned* partial = (unsigned*)(bucket + n_edges);        // [2*2*NBC*SP] u32

    int ntiles = (n_coarse + 15) / 16;

    hipLaunchKernelGGL(k_hist, dim3(4 * NBC), dim3(512), 0, stream,
                       src, dst, partial, n_edges, nhalf, chunk);
    hipLaunchKernelGGL(k_hreduce, dim3(4 * nbh), dim3(256), 0, stream,
                       partial, rso, deg, ri, map, off0, blksum, nhalf, nbh, n_fine, n_coarse);
    hipLaunchKernelGGL(k_gemm, dim3((ntiles + 3) / 4), dim3(256), 0, stream,
                       feat, sel, rso, W, hwb, map, blksum, n_coarse, nbw);
    hipLaunchKernelGGL(k_bucket, dim3(4 * NBC), dim3(512), 0, stream,
                       src, dst, map, off0, blksum, partial, bucket, n_edges, nhalf, nbh, chunk);
    hipLaunchKernelGGL(k_gather, dim3((n_fine * 16 + 255) / 256), dim3(256), 0, stream,
                       off0, blksum, deg, ri, bucket, (const uint4*)hwb, bias, out,
                       n_fine, nhalf, nbh);
}